// Round 1
// baseline (1117.911 us; speedup 1.0000x reference)
//
#include <hip/hip_runtime.h>
#include <stdint.h>

// Problem constants (fixed by reference)
#define BB 8
#define NN 20000
#define CC 256
#define EE 320000
#define KK 3
#define MROWS (BB * NN)   // 160000

// ---------- bf16 helpers (raw ushort representation) ----------
__device__ __forceinline__ float bf2f(ushort u) {
    union { uint32_t ui; float f; } v; v.ui = ((uint32_t)u) << 16; return v.f;
}
__device__ __forceinline__ ushort f2bf(float f) {
    union { uint32_t ui; float f; } v; v.f = f;
    uint32_t r = (v.ui + 0x7FFFu + ((v.ui >> 16) & 1u)) >> 16;
    return (ushort)r;
}

typedef __bf16 bf16x8 __attribute__((ext_vector_type(8)));
typedef float  f32x4  __attribute__((ext_vector_type(4)));

__device__ __forceinline__ void gload16(const void* gptr, void* lptr) {
    __builtin_amdgcn_global_load_lds(
        (const __attribute__((address_space(1))) void*)gptr,
        (__attribute__((address_space(3))) void*)lptr, 16, 0, 0);
}

// ---------- edge width detect: int64 high words are all zero ----------
__global__ void detect_k(const int* __restrict__ raw, int* __restrict__ flag) {
    int i = blockIdx.x * 256 + threadIdx.x;
    int v = 0;
    int idx = 2 * i + 1;
    if (i < EE) v = raw[idx];            // odd 32-bit word in [0, 2E)
    unsigned long long m = __ballot(v != 0);
    if ((threadIdx.x & 63) == 0 && m) atomicOr(flag, 1);
}

// normalize edges to int32 src[]/dst[]
__global__ void convert_k(const int* __restrict__ raw, const int* __restrict__ flag,
                          int* __restrict__ src, int* __restrict__ dst) {
    int e = blockIdx.x * 256 + threadIdx.x;
    if (e >= EE) return;
    if (*flag == 0) {  // int64 (little-endian low words)
        src[e] = raw[2 * e];
        dst[e] = raw[2 * EE + 2 * e];
    } else {           // int32
        src[e] = raw[e];
        dst[e] = raw[EE + e];
    }
}

__global__ void count_k(const int* __restrict__ src, const int* __restrict__ dst,
                        int* __restrict__ deg_out, int* __restrict__ cnt_in) {
    int e = blockIdx.x * 256 + threadIdx.x;
    if (e >= EE) return;
    atomicAdd(&deg_out[src[e]], 1);
    atomicAdd(&cnt_in[dst[e]], 1);
}

// single-block exclusive scan of cnt_in -> row_ptr, plus dis = rsqrt(deg_out)
__global__ void scan_k(const int* __restrict__ cnt_in, const int* __restrict__ deg_out,
                       int* __restrict__ row_ptr, float* __restrict__ dis) {
    __shared__ int sm[1024];
    int tid = threadIdx.x;
    int carry = 0;
    for (int base = 0; base < NN; base += 1024) {
        int i = base + tid;
        int v = (i < NN) ? cnt_in[i] : 0;
        sm[tid] = v;
        __syncthreads();
        for (int off = 1; off < 1024; off <<= 1) {
            int add = (tid >= off) ? sm[tid - off] : 0;
            __syncthreads();
            sm[tid] += add;
            __syncthreads();
        }
        int incl = sm[tid];
        if (i < NN) row_ptr[i] = carry + incl - v;
        carry += sm[1023];
        __syncthreads();
    }
    if (tid == 0) row_ptr[NN] = carry;
    for (int i = tid; i < NN; i += 1024) {
        int d = deg_out[i];
        dis[i] = (d > 0) ? rsqrtf((float)d) : 0.0f;
    }
}

__global__ void fill_k(const int* __restrict__ src, const int* __restrict__ dst,
                       const int* __restrict__ row_ptr, int* __restrict__ fillc,
                       const float* __restrict__ dis,
                       int* __restrict__ col, float* __restrict__ w) {
    int e = blockIdx.x * 256 + threadIdx.x;
    if (e >= EE) return;
    int s = src[e], d = dst[e];
    int pos = row_ptr[d] + atomicAdd(&fillc[d], 1);
    col[pos] = s;
    w[pos] = -dis[s] * dis[d];
}

// fp32 -> bf16 cast of features
__global__ void cvt_k(const float* __restrict__ x, ushort* __restrict__ y) {
    size_t idx = ((size_t)blockIdx.x * 256 + threadIdx.x) * 4;
    float4 v = *(const float4*)(x + idx);
    ushort4 o = make_ushort4(f2bf(v.x), f2bf(v.y), f2bf(v.z), f2bf(v.w));
    *(ushort4*)(y + idx) = o;
}

// Build WcatT[n][k] bf16, n in [0,256), k in [0,768):
//   block 0: W1[0]-W1[2], block 1: W1[1], block 2: 2*W1[2]   (Tx2 = 2*P2 - Tx0 folded)
__global__ void wprep_k(const float* __restrict__ W, ushort* __restrict__ wt) {
    int idx = blockIdx.x * 256 + threadIdx.x;
    if (idx >= 256 * 768) return;
    int n = idx / 768, k = idx % 768;
    int sel = k >> 8, kk = k & 255;
    const float* W1 = W + KK * CC * CC;  // layer 1
    float v;
    if (sel == 0)      v = W1[kk * CC + n] - W1[2 * CC * CC + kk * CC + n];
    else if (sel == 1) v = W1[CC * CC + kk * CC + n];
    else               v = 2.0f * W1[2 * CC * CC + kk * CC + n];
    wt[idx] = f2bf(v);
}

// y[b,i,:] = sum_{e: dst=i} w[e] * x[b, col[e], :]   (one wave per (b,i) row)
__global__ void __launch_bounds__(256) prop_k(const ushort* __restrict__ x, ushort* __restrict__ y,
                                              const int* __restrict__ row_ptr,
                                              const int* __restrict__ col,
                                              const float* __restrict__ w) {
    int wid = threadIdx.x >> 6, lane = threadIdx.x & 63;
    int bi = blockIdx.x * 4 + wid;            // grid = MROWS/4 exactly
    int b = bi / NN, i = bi - b * NN;
    int beg = row_ptr[i], end = row_ptr[i + 1];
    const ushort* xb = x + (size_t)b * NN * CC + lane * 4;
    float a0 = 0, a1 = 0, a2 = 0, a3 = 0;
    for (int j = beg; j < end; j++) {
        int s = col[j];
        float wt = w[j];
        ushort4 v = *(const ushort4*)(xb + (size_t)s * CC);
        a0 += wt * bf2f(v.x);
        a1 += wt * bf2f(v.y);
        a2 += wt * bf2f(v.z);
        a3 += wt * bf2f(v.w);
    }
    ushort4 o = make_ushort4(f2bf(a0), f2bf(a1), f2bf(a2), f2bf(a3));
    *(ushort4*)(y + (size_t)bi * CC + lane * 4) = o;
}

// out[M,256] = [A0|A1|A2] (bf16, each [M,256]) @ WcatT^T (bf16 [256][768]) -> fp32
// 128x128 tile, BK=32, 256 threads (2x2 waves, each 64x64 via 4x4 mfma 16x16x32)
__global__ void __launch_bounds__(256) gemm_k(const ushort* __restrict__ a0,
                                              const ushort* __restrict__ a1,
                                              const ushort* __restrict__ a2,
                                              const ushort* __restrict__ wt,
                                              float* __restrict__ out) {
    __shared__ ushort As[128 * 32];
    __shared__ ushort Bs[128 * 32];
    const int tid = threadIdx.x;
    const int wid = tid >> 6, lane = tid & 63;
    const int wrow = wid >> 1, wcol = wid & 1;
    const int row0 = blockIdx.x * 128, col0 = blockIdx.y * 128;
    const int quad = lane >> 4, l16 = lane & 15;

    f32x4 acc[4][4] = {};

    for (int kt = 0; kt < 24; kt++) {
        const ushort* ab = (kt < 8) ? a0 : ((kt < 16) ? a1 : a2);
        const int kl = (kt & 7) * 32;        // k offset within the 256-col buffer
        const int kg = kt * 32;              // global k for WcatT
        __syncthreads();
#pragma unroll
        for (int q = 0; q < 2; q++) {
            int c = wid * 128 + q * 64 + lane;     // 16B chunk id, 0..511
            int m = c >> 2, kq = (c & 3) * 8;
            gload16(ab + (size_t)(row0 + m) * CC + kl + kq,
                    &As[(wid * 128 + q * 64) * 8]);
            gload16(wt + (size_t)(col0 + m) * 768 + kg + kq,
                    &Bs[(wid * 128 + q * 64) * 8]);
        }
        __syncthreads();

        bf16x8 af[4], bfr[4];
#pragma unroll
        for (int mt = 0; mt < 4; mt++)
            af[mt] = *(const bf16x8*)&As[(wrow * 64 + mt * 16 + l16) * 32 + quad * 8];
#pragma unroll
        for (int nt = 0; nt < 4; nt++)
            bfr[nt] = *(const bf16x8*)&Bs[(wcol * 64 + nt * 16 + l16) * 32 + quad * 8];
#pragma unroll
        for (int mt = 0; mt < 4; mt++)
#pragma unroll
            for (int nt = 0; nt < 4; nt++)
                acc[mt][nt] = __builtin_amdgcn_mfma_f32_16x16x32_bf16(
                    af[mt], bfr[nt], acc[mt][nt], 0, 0, 0);
    }

    // C/D layout: col = lane&15, row = (lane>>4)*4 + reg   [measured m89]
#pragma unroll
    for (int mt = 0; mt < 4; mt++) {
#pragma unroll
        for (int nt = 0; nt < 4; nt++) {
#pragma unroll
            for (int r = 0; r < 4; r++) {
                size_t row = (size_t)row0 + wrow * 64 + mt * 16 + quad * 4 + r;
                size_t colo = (size_t)col0 + wcol * 64 + nt * 16 + l16;
                out[row * CC + colo] = acc[mt][nt][r];
            }
        }
    }
}

// in-place LayerNorm over C with conv bias folded in (one wave per row)
__global__ void __launch_bounds__(256) ln_k(float* __restrict__ out,
                                            const float* __restrict__ bias,
                                            const float* __restrict__ lnw,
                                            const float* __restrict__ lnb) {
    int wid = threadIdx.x >> 6, lane = threadIdx.x & 63;
    size_t row = (size_t)blockIdx.x * 4 + wid;   // grid = MROWS/4
    float* p = out + row * CC + lane * 4;
    float4 v = *(float4*)p;
    float4 bb = *(const float4*)(bias + lane * 4);
    v.x += bb.x; v.y += bb.y; v.z += bb.z; v.w += bb.w;
    float s = v.x + v.y + v.z + v.w;
    float sq = v.x * v.x + v.y * v.y + v.z * v.z + v.w * v.w;
    for (int off = 32; off; off >>= 1) {
        s += __shfl_xor(s, off, 64);
        sq += __shfl_xor(sq, off, 64);
    }
    float mean = s * (1.0f / CC);
    float var = sq * (1.0f / CC) - mean * mean;
    float rs = rsqrtf(var + 1e-5f);
    float4 lw = *(const float4*)(lnw + lane * 4);
    float4 lb = *(const float4*)(lnb + lane * 4);
    v.x = (v.x - mean) * rs * lw.x + lb.x;
    v.y = (v.y - mean) * rs * lw.y + lb.y;
    v.z = (v.z - mean) * rs * lw.z + lb.z;
    v.w = (v.w - mean) * rs * lw.w + lb.w;
    *(float4*)p = v;
}

extern "C" void kernel_launch(void* const* d_in, const int* in_sizes, int n_in,
                              void* d_out, int out_size, void* d_ws, size_t ws_size,
                              hipStream_t stream) {
    const float* feats = (const float*)d_in[0];
    const float* W     = (const float*)d_in[1];   // [L,K,C,C]
    const float* bvec  = (const float*)d_in[2];   // [L,C]
    const float* lnw   = (const float*)d_in[3];   // [L,C]
    const float* lnb   = (const float*)d_in[4];   // [L,C]
    const int*   eidx  = (const int*)d_in[5];     // (2,E) int32 or int64 (detected)
    float* outp = (float*)d_out;

    // ---- workspace carve-up ----
    int* flag    = (int*)d_ws;            // 64 ints (only [0] used)
    int* deg_out = flag + 64;             // N
    int* cnt_in  = deg_out + NN;          // N
    int* fillc   = cnt_in + NN;           // N   (memset covers up to here)
    int* row_ptr = fillc + NN;            // N+1 (+pad)
    int* srcw    = row_ptr + (NN + 64);   // E
    int* dstw    = srcw + EE;             // E
    int* colw    = dstw + EE;             // E
    float* disw  = (float*)(colw + EE);   // N (+pad)
    float* ww    = disw + (NN + 64);      // E
    uintptr_t bf_base = ((uintptr_t)(ww + EE) + 255) & ~(uintptr_t)255;
    ushort* featsb = (ushort*)bf_base;                 // M*C bf16
    ushort* tx1b   = featsb + (size_t)MROWS * CC;      // M*C
    ushort* p2b    = tx1b + (size_t)MROWS * CC;        // M*C
    ushort* wcat   = p2b + (size_t)MROWS * CC;         // 256*768

    hipMemsetAsync(flag, 0, (size_t)(64 + 3 * NN) * sizeof(int), stream);

    int eb = (EE + 255) / 256;  // 1250
    detect_k<<<eb, 256, 0, stream>>>(eidx, flag);
    convert_k<<<eb, 256, 0, stream>>>(eidx, flag, srcw, dstw);
    count_k<<<eb, 256, 0, stream>>>(srcw, dstw, deg_out, cnt_in);
    scan_k<<<1, 1024, 0, stream>>>(cnt_in, deg_out, row_ptr, disw);
    fill_k<<<eb, 256, 0, stream>>>(srcw, dstw, row_ptr, fillc, disw, colw, ww);

    cvt_k<<<MROWS * CC / 1024, 256, 0, stream>>>(feats, featsb);     // 40000 blocks
    wprep_k<<<(256 * 768 + 255) / 256, 256, 0, stream>>>(W, wcat);   // 768 blocks

    prop_k<<<MROWS / 4, 256, 0, stream>>>(featsb, tx1b, row_ptr, colw, ww);
    prop_k<<<MROWS / 4, 256, 0, stream>>>(tx1b, p2b, row_ptr, colw, ww);

    gemm_k<<<dim3(MROWS / 128, CC / 128), 256, 0, stream>>>(featsb, tx1b, p2b, wcat, outp);

    // layer-1 params (only last layer matters — layer 0 output is overwritten)
    ln_k<<<MROWS / 4, 256, 0, stream>>>(outp, bvec + CC, lnw + CC, lnb + CC);
}

// Round 2
// 973.418 us; speedup vs baseline: 1.1484x; 1.1484x over previous
//
#include <hip/hip_runtime.h>
#include <stdint.h>

// Problem constants (fixed by reference)
#define BB 8
#define NN 20000
#define CC 256
#define EE 320000
#define KK 3
#define MROWS (BB * NN)   // 160000
#define ROWU (BB * CC)    // 2048 ushorts per node-group (4 KB)

// ---------- bf16 helpers (raw ushort representation) ----------
__device__ __forceinline__ float bf2f(ushort u) {
    union { uint32_t ui; float f; } v; v.ui = ((uint32_t)u) << 16; return v.f;
}
__device__ __forceinline__ ushort f2bf(float f) {
    union { uint32_t ui; float f; } v; v.f = f;
    uint32_t r = (v.ui + 0x7FFFu + ((v.ui >> 16) & 1u)) >> 16;
    return (ushort)r;
}

typedef __bf16 bf16x8 __attribute__((ext_vector_type(8)));
typedef float  f32x4  __attribute__((ext_vector_type(4)));

__device__ __forceinline__ void gload16(const void* gptr, void* lptr) {
    __builtin_amdgcn_global_load_lds(
        (const __attribute__((address_space(1))) void*)gptr,
        (__attribute__((address_space(3))) void*)lptr, 16, 0, 0);
}

// ---------- edge width detect: int64 high words are all zero ----------
__global__ void detect_k(const int* __restrict__ raw, int* __restrict__ flag) {
    int i = blockIdx.x * 256 + threadIdx.x;
    int v = 0;
    int idx = 2 * i + 1;
    if (i < EE) v = raw[idx];            // odd 32-bit word in [0, 2E)
    unsigned long long m = __ballot(v != 0);
    if ((threadIdx.x & 63) == 0 && m) atomicOr(flag, 1);
}

// normalize edges to int32 src[]/dst[]
__global__ void convert_k(const int* __restrict__ raw, const int* __restrict__ flag,
                          int* __restrict__ src, int* __restrict__ dst) {
    int e = blockIdx.x * 256 + threadIdx.x;
    if (e >= EE) return;
    if (*flag == 0) {  // int64 (little-endian low words)
        src[e] = raw[2 * e];
        dst[e] = raw[2 * EE + 2 * e];
    } else {           // int32
        src[e] = raw[e];
        dst[e] = raw[EE + e];
    }
}

__global__ void count_k(const int* __restrict__ src, const int* __restrict__ dst,
                        int* __restrict__ deg_out, int* __restrict__ cnt_in) {
    int e = blockIdx.x * 256 + threadIdx.x;
    if (e >= EE) return;
    atomicAdd(&deg_out[src[e]], 1);
    atomicAdd(&cnt_in[dst[e]], 1);
}

// single-block scan, shfl-based: thread t owns 20 contiguous elements.
__global__ void __launch_bounds__(1024) scan_k(const int* __restrict__ cnt_in,
                                               const int* __restrict__ deg_out,
                                               int* __restrict__ row_ptr,
                                               float* __restrict__ dis) {
    __shared__ int wpart[16];
    const int t = threadIdx.x;
    const int lane = t & 63, wid = t >> 6;
    const int base = t * 20;
    int local[20];
    int sum = 0;
#pragma unroll
    for (int i = 0; i < 20; i++) {
        int idx = base + i;
        int v = (idx < NN) ? cnt_in[idx] : 0;
        local[i] = sum;
        sum += v;
    }
    int sc = sum;  // inclusive wave scan of per-thread sums
#pragma unroll
    for (int off = 1; off < 64; off <<= 1) {
        int u = __shfl_up(sc, off, 64);
        if (lane >= off) sc += u;
    }
    if (lane == 63) wpart[wid] = sc;
    __syncthreads();
    if (wid == 0 && lane < 16) {
        int v = wpart[lane];
#pragma unroll
        for (int off = 1; off < 16; off <<= 1) {
            int u = __shfl_up(v, off, 64);
            if (lane >= off) v += u;
        }
        wpart[lane] = v;
    }
    __syncthreads();
    int wbase = (wid > 0) ? wpart[wid - 1] : 0;
    int tbase = wbase + sc - sum;  // exclusive base for this thread
#pragma unroll
    for (int i = 0; i < 20; i++) {
        int idx = base + i;
        if (idx < NN) row_ptr[idx] = tbase + local[i];
    }
    if (t == 1023) row_ptr[NN] = tbase + sum;
    for (int i = t; i < NN; i += 1024) {
        int d = deg_out[i];
        dis[i] = (d > 0) ? rsqrtf((float)d) : 0.0f;
    }
}

__global__ void fill_k(const int* __restrict__ src, const int* __restrict__ dst,
                       const int* __restrict__ row_ptr, int* __restrict__ fillc,
                       const float* __restrict__ dis,
                       int* __restrict__ col, float* __restrict__ w) {
    int e = blockIdx.x * 256 + threadIdx.x;
    if (e >= EE) return;
    int s = src[e], d = dst[e];
    int pos = row_ptr[d] + atomicAdd(&fillc[d], 1);
    col[pos] = s;
    w[pos] = -dis[s] * dis[d];
}

// fp32 [b,n,c] -> bf16 node-major [n,b,c]
__global__ void cvt_k(const float* __restrict__ x, ushort* __restrict__ y) {
    size_t idx = ((size_t)blockIdx.x * 256 + threadIdx.x) * 4;
    int row = (int)(idx >> 8);     // b*N + n  (< 160000)
    int c = (int)(idx & 255);
    int b = row / NN, n = row - b * NN;
    float4 v = *(const float4*)(x + idx);
    ushort4 o = make_ushort4(f2bf(v.x), f2bf(v.y), f2bf(v.z), f2bf(v.w));
    *(ushort4*)(y + ((size_t)(n * BB + b) * CC + c)) = o;
}

// Build WcatT[n][k] bf16, n in [0,256), k in [0,768):
//   block 0: W1[0]-W1[2], block 1: W1[1], block 2: 2*W1[2]   (Tx2 = 2*P2 - Tx0 folded)
__global__ void wprep_k(const float* __restrict__ W, ushort* __restrict__ wt) {
    int idx = blockIdx.x * 256 + threadIdx.x;
    if (idx >= 256 * 768) return;
    int n = idx / 768, k = idx % 768;
    int sel = k >> 8, kk = k & 255;
    const float* W1 = W + KK * CC * CC;  // layer 1
    float v;
    if (sel == 0)      v = W1[kk * CC + n] - W1[2 * CC * CC + kk * CC + n];
    else if (sel == 1) v = W1[CC * CC + kk * CC + n];
    else               v = 2.0f * W1[2 * CC * CC + kk * CC + n];
    wt[idx] = f2bf(v);
}

// Node-major prop: y[n, :, :] = sum_{e: dst=n} w[e] * x[col[e], :, :]
// one 256-thread block per dst node; thread t covers bytes [t*16, t*16+16)
// of the 4 KB node-group. Edge loop unrolled by 4 for MLP.
__global__ void __launch_bounds__(256) prop_k(const ushort* __restrict__ x,
                                              ushort* __restrict__ y,
                                              const int* __restrict__ row_ptr,
                                              const int* __restrict__ col,
                                              const float* __restrict__ w) {
    const int n = blockIdx.x;
    const int t = threadIdx.x;
    const int beg = row_ptr[n], end = row_ptr[n + 1];
    const ushort* xb = x + t * 8;   // 8 ushorts = 16 B per thread
    float a0 = 0, a1 = 0, a2 = 0, a3 = 0, a4 = 0, a5 = 0, a6 = 0, a7 = 0;
    int j = beg;
    for (; j + 4 <= end; j += 4) {
        int s0 = col[j], s1 = col[j + 1], s2 = col[j + 2], s3 = col[j + 3];
        float w0 = w[j], w1 = w[j + 1], w2 = w[j + 2], w3 = w[j + 3];
        uint4 v0 = *(const uint4*)(xb + (size_t)s0 * ROWU);
        uint4 v1 = *(const uint4*)(xb + (size_t)s1 * ROWU);
        uint4 v2 = *(const uint4*)(xb + (size_t)s2 * ROWU);
        uint4 v3 = *(const uint4*)(xb + (size_t)s3 * ROWU);
        a0 += w0 * bf2f((ushort)v0.x) + w1 * bf2f((ushort)v1.x) + w2 * bf2f((ushort)v2.x) + w3 * bf2f((ushort)v3.x);
        a1 += w0 * bf2f((ushort)(v0.x >> 16)) + w1 * bf2f((ushort)(v1.x >> 16)) + w2 * bf2f((ushort)(v2.x >> 16)) + w3 * bf2f((ushort)(v3.x >> 16));
        a2 += w0 * bf2f((ushort)v0.y) + w1 * bf2f((ushort)v1.y) + w2 * bf2f((ushort)v2.y) + w3 * bf2f((ushort)v3.y);
        a3 += w0 * bf2f((ushort)(v0.y >> 16)) + w1 * bf2f((ushort)(v1.y >> 16)) + w2 * bf2f((ushort)(v2.y >> 16)) + w3 * bf2f((ushort)(v3.y >> 16));
        a4 += w0 * bf2f((ushort)v0.z) + w1 * bf2f((ushort)v1.z) + w2 * bf2f((ushort)v2.z) + w3 * bf2f((ushort)v3.z);
        a5 += w0 * bf2f((ushort)(v0.z >> 16)) + w1 * bf2f((ushort)(v1.z >> 16)) + w2 * bf2f((ushort)(v2.z >> 16)) + w3 * bf2f((ushort)(v3.z >> 16));
        a6 += w0 * bf2f((ushort)v0.w) + w1 * bf2f((ushort)v1.w) + w2 * bf2f((ushort)v2.w) + w3 * bf2f((ushort)v3.w);
        a7 += w0 * bf2f((ushort)(v0.w >> 16)) + w1 * bf2f((ushort)(v1.w >> 16)) + w2 * bf2f((ushort)(v2.w >> 16)) + w3 * bf2f((ushort)(v3.w >> 16));
    }
    for (; j < end; j++) {
        int s = col[j];
        float wt = w[j];
        uint4 v = *(const uint4*)(xb + (size_t)s * ROWU);
        a0 += wt * bf2f((ushort)v.x);
        a1 += wt * bf2f((ushort)(v.x >> 16));
        a2 += wt * bf2f((ushort)v.y);
        a3 += wt * bf2f((ushort)(v.y >> 16));
        a4 += wt * bf2f((ushort)v.z);
        a5 += wt * bf2f((ushort)(v.z >> 16));
        a6 += wt * bf2f((ushort)v.w);
        a7 += wt * bf2f((ushort)(v.w >> 16));
    }
    uint4 o;
    o.x = (uint32_t)f2bf(a0) | ((uint32_t)f2bf(a1) << 16);
    o.y = (uint32_t)f2bf(a2) | ((uint32_t)f2bf(a3) << 16);
    o.z = (uint32_t)f2bf(a4) | ((uint32_t)f2bf(a5) << 16);
    o.w = (uint32_t)f2bf(a6) | ((uint32_t)f2bf(a7) << 16);
    *(uint4*)(y + (size_t)n * ROWU + t * 8) = o;
}

// out = [A0|A1|A2] (bf16, node-major rows m'=n*8+b) @ WcatT^T -> fp32 to d_out
// with row un-permutation (m' -> b*N+n) in the epilogue.
// 128x128 tile, BK=32, 256 threads (2x2 waves, each 64x64 via 4x4 mfma 16x16x32)
__global__ void __launch_bounds__(256) gemm_k(const ushort* __restrict__ a0,
                                              const ushort* __restrict__ a1,
                                              const ushort* __restrict__ a2,
                                              const ushort* __restrict__ wt,
                                              float* __restrict__ out) {
    __shared__ ushort As[128 * 32];
    __shared__ ushort Bs[128 * 32];
    const int tid = threadIdx.x;
    const int wid = tid >> 6, lane = tid & 63;
    const int wrow = wid >> 1, wcol = wid & 1;
    const int row0 = blockIdx.x * 128, col0 = blockIdx.y * 128;
    const int quad = lane >> 4, l16 = lane & 15;

    f32x4 acc[4][4] = {};

    for (int kt = 0; kt < 24; kt++) {
        const ushort* ab = (kt < 8) ? a0 : ((kt < 16) ? a1 : a2);
        const int kl = (kt & 7) * 32;        // k offset within the 256-col buffer
        const int kg = kt * 32;              // global k for WcatT
        __syncthreads();
#pragma unroll
        for (int q = 0; q < 2; q++) {
            int c = wid * 128 + q * 64 + lane;     // 16B chunk id, 0..511
            int m = c >> 2, kq = (c & 3) * 8;
            gload16(ab + (size_t)(row0 + m) * CC + kl + kq,
                    &As[(wid * 128 + q * 64) * 8]);
            gload16(wt + (size_t)(col0 + m) * 768 + kg + kq,
                    &Bs[(wid * 128 + q * 64) * 8]);
        }
        __syncthreads();

        bf16x8 af[4], bfr[4];
#pragma unroll
        for (int mt = 0; mt < 4; mt++)
            af[mt] = *(const bf16x8*)&As[(wrow * 64 + mt * 16 + l16) * 32 + quad * 8];
#pragma unroll
        for (int nt = 0; nt < 4; nt++)
            bfr[nt] = *(const bf16x8*)&Bs[(wcol * 64 + nt * 16 + l16) * 32 + quad * 8];
#pragma unroll
        for (int mt = 0; mt < 4; mt++)
#pragma unroll
            for (int nt = 0; nt < 4; nt++)
                acc[mt][nt] = __builtin_amdgcn_mfma_f32_16x16x32_bf16(
                    af[mt], bfr[nt], acc[mt][nt], 0, 0, 0);
    }

    // C/D layout: col = lane&15, row = (lane>>4)*4 + reg   [measured m89]
#pragma unroll
    for (int mt = 0; mt < 4; mt++) {
#pragma unroll
        for (int nt = 0; nt < 4; nt++) {
#pragma unroll
            for (int r = 0; r < 4; r++) {
                int m = row0 + wrow * 64 + mt * 16 + quad * 4 + r;  // node-major
                int n = m >> 3, b = m & 7;
                size_t orow = (size_t)b * NN + n;
                size_t colo = (size_t)col0 + wcol * 64 + nt * 16 + l16;
                out[orow * CC + colo] = acc[mt][nt][r];
            }
        }
    }
}

// in-place LayerNorm over C with conv bias folded in (one wave per row)
__global__ void __launch_bounds__(256) ln_k(float* __restrict__ out,
                                            const float* __restrict__ bias,
                                            const float* __restrict__ lnw,
                                            const float* __restrict__ lnb) {
    int wid = threadIdx.x >> 6, lane = threadIdx.x & 63;
    size_t row = (size_t)blockIdx.x * 4 + wid;   // grid = MROWS/4
    float* p = out + row * CC + lane * 4;
    float4 v = *(float4*)p;
    float4 bb = *(const float4*)(bias + lane * 4);
    v.x += bb.x; v.y += bb.y; v.z += bb.z; v.w += bb.w;
    float s = v.x + v.y + v.z + v.w;
    float sq = v.x * v.x + v.y * v.y + v.z * v.z + v.w * v.w;
    for (int off = 32; off; off >>= 1) {
        s += __shfl_xor(s, off, 64);
        sq += __shfl_xor(sq, off, 64);
    }
    float mean = s * (1.0f / CC);
    float var = sq * (1.0f / CC) - mean * mean;
    float rs = rsqrtf(var + 1e-5f);
    float4 lw = *(const float4*)(lnw + lane * 4);
    float4 lb = *(const float4*)(lnb + lane * 4);
    v.x = (v.x - mean) * rs * lw.x + lb.x;
    v.y = (v.y - mean) * rs * lw.y + lb.y;
    v.z = (v.z - mean) * rs * lw.z + lb.z;
    v.w = (v.w - mean) * rs * lw.w + lb.w;
    *(float4*)p = v;
}

extern "C" void kernel_launch(void* const* d_in, const int* in_sizes, int n_in,
                              void* d_out, int out_size, void* d_ws, size_t ws_size,
                              hipStream_t stream) {
    const float* feats = (const float*)d_in[0];
    const float* W     = (const float*)d_in[1];   // [L,K,C,C]
    const float* bvec  = (const float*)d_in[2];   // [L,C]
    const float* lnw   = (const float*)d_in[3];   // [L,C]
    const float* lnb   = (const float*)d_in[4];   // [L,C]
    const int*   eidx  = (const int*)d_in[5];     // (2,E) int32 or int64 (detected)
    float* outp = (float*)d_out;

    // ---- workspace carve-up ----
    int* flag    = (int*)d_ws;            // 64 ints (only [0] used)
    int* deg_out = flag + 64;             // N
    int* cnt_in  = deg_out + NN;          // N
    int* fillc   = cnt_in + NN;           // N   (memset covers up to here)
    int* row_ptr = fillc + NN;            // N+1 (+pad)
    int* srcw    = row_ptr + (NN + 64);   // E
    int* dstw    = srcw + EE;             // E
    int* colw    = dstw + EE;             // E
    float* disw  = (float*)(colw + EE);   // N (+pad)
    float* ww    = disw + (NN + 64);      // E
    uintptr_t bf_base = ((uintptr_t)(ww + EE) + 255) & ~(uintptr_t)255;
    ushort* featsb = (ushort*)bf_base;                 // M*C bf16  [n,b,c]
    ushort* tx1b   = featsb + (size_t)MROWS * CC;      // M*C
    ushort* p2b    = tx1b + (size_t)MROWS * CC;        // M*C
    ushort* wcat   = p2b + (size_t)MROWS * CC;         // 256*768

    hipMemsetAsync(flag, 0, (size_t)(64 + 3 * NN) * sizeof(int), stream);

    int eb = (EE + 255) / 256;  // 1250
    detect_k<<<eb, 256, 0, stream>>>(eidx, flag);
    convert_k<<<eb, 256, 0, stream>>>(eidx, flag, srcw, dstw);
    count_k<<<eb, 256, 0, stream>>>(srcw, dstw, deg_out, cnt_in);
    scan_k<<<1, 1024, 0, stream>>>(cnt_in, deg_out, row_ptr, disw);
    fill_k<<<eb, 256, 0, stream>>>(srcw, dstw, row_ptr, fillc, disw, colw, ww);

    cvt_k<<<MROWS * CC / 1024, 256, 0, stream>>>(feats, featsb);     // 40000 blocks
    wprep_k<<<(256 * 768 + 255) / 256, 256, 0, stream>>>(W, wcat);   // 768 blocks

    prop_k<<<NN, 256, 0, stream>>>(featsb, tx1b, row_ptr, colw, ww);
    prop_k<<<NN, 256, 0, stream>>>(tx1b, p2b, row_ptr, colw, ww);

    gemm_k<<<dim3(MROWS / 128, CC / 128), 256, 0, stream>>>(featsb, tx1b, p2b, wcat, outp);

    // layer-1 params (only last layer matters — layer 0 output is overwritten)
    ln_k<<<MROWS / 4, 256, 0, stream>>>(outp, bvec + CC, lnw + CC, lnb + CC);
}